// Round 3
// baseline (932.093 us; speedup 1.0000x reference)
//
#include <hip/hip_runtime.h>

#define N_TAG 128
#define T_LEN 512
#define START_TAG 126
#define STOP_TAG 127

// One block per batch. 128 threads: thread i owns output tag i.
// State kept in exp-space: u[j] = exp(alpha[j] - logZ), renormalized by max
// every 4 steps (worst-case growth per step ~e^15 -> 4 steps < e^60 < e^88).
// Recurrence: v_i = sum_j u_j * E[i][j],  u'_i = v_i * exp(feat_t[i]),
// where E[i][j] = exp(trans[i][j]) lives in per-thread registers (reused T times).
__global__ __launch_bounds__(N_TAG) void crf_nll_kernel(
    const float* __restrict__ feats, const float* __restrict__ trans,
    const int* __restrict__ tags, float* __restrict__ out, int T) {
  const int b = blockIdx.x;
  const int i = threadIdx.x;

  __shared__ float u_lds[2][N_TAG];
  __shared__ float red_lds[2];

  // ---- prologue: E row i = exp(trans[i][:]) into 128 VGPRs ----
  float E[N_TAG];
  {
    const float4* trow = reinterpret_cast<const float4*>(trans + (size_t)i * N_TAG);
#pragma unroll
    for (int c = 0; c < N_TAG / 4; ++c) {
      float4 v = trow[c];
      E[4 * c + 0] = __expf(v.x);
      E[4 * c + 1] = __expf(v.y);
      E[4 * c + 2] = __expf(v.z);
      E[4 * c + 3] = __expf(v.w);
    }
  }

  // init: alpha_0 = NEG_INF except START=0  ->  u = one-hot(START)
  u_lds[0][i] = (i == START_TAG) ? 1.0f : 0.0f;
  float logZ = 0.0f;
  __syncthreads();

  const float* fb = feats + (size_t)b * T * N_TAG;
  float feat_cur = fb[i];  // t = 0
  int cur = 0;
  float up = 0.0f;

  for (int t = 0; t < T; ++t) {
    // prefetch next feat (independent of this step's chain)
    float feat_next = 0.0f;
    if (t + 1 < T) feat_next = fb[(size_t)(t + 1) * N_TAG + i];
    float ef = __expf(feat_cur);

    // v_i = sum_j u[j] * E[j]  (u broadcast from LDS, b128 same-address reads)
    float v0 = 0.0f, v1 = 0.0f, v2 = 0.0f, v3 = 0.0f;
    const float4* u4 = reinterpret_cast<const float4*>(u_lds[cur]);
#pragma unroll
    for (int c = 0; c < N_TAG / 4; ++c) {
      float4 u = u4[c];
      v0 = __builtin_fmaf(u.x, E[4 * c + 0], v0);
      v1 = __builtin_fmaf(u.y, E[4 * c + 1], v1);
      v2 = __builtin_fmaf(u.z, E[4 * c + 2], v2);
      v3 = __builtin_fmaf(u.w, E[4 * c + 3], v3);
    }
    up = ((v0 + v1) + (v2 + v3)) * ef;

    if ((t & 3) == 3) {
      // renormalize: c = max_i u'_i ; u' /= c ; logZ += log(c)
      float m = up;
#pragma unroll
      for (int s = 32; s; s >>= 1) m = fmaxf(m, __shfl_xor(m, s));
      if ((i & 63) == 0) red_lds[i >> 6] = m;
      __syncthreads();
      float c = fmaxf(red_lds[0], red_lds[1]);
      up *= (1.0f / c);
      logZ += __logf(c);
    }

    u_lds[cur ^ 1][i] = up;
    __syncthreads();
    cur ^= 1;
    feat_cur = feat_next;
  }

  // ---- forward score: log(sum_j u_j * exp(trans[STOP][j])) + logZ ----
  float w = up * __expf(trans[STOP_TAG * N_TAG + i]);
#pragma unroll
  for (int s = 32; s; s >>= 1) w += __shfl_xor(w, s);
  __syncthreads();  // red_lds reuse guard
  if ((i & 63) == 0) red_lds[i >> 6] = w;
  __syncthreads();
  float forward = __logf(red_lds[0] + red_lds[1]) + logZ;

  // ---- gold path score ----
  const int* tg = tags + (size_t)b * T;
  float g = 0.0f;
  for (int t = i; t < T; t += N_TAG) {
    int tag = tg[t];
    int prev = (t == 0) ? START_TAG : tg[t - 1];
    g += trans[tag * N_TAG + prev] + fb[(size_t)t * N_TAG + tag];
  }
  if (i == 0) g += trans[STOP_TAG * N_TAG + tg[T - 1]];
#pragma unroll
  for (int s = 32; s; s >>= 1) g += __shfl_xor(g, s);
  __syncthreads();  // red_lds reuse guard (forward already in registers)
  if ((i & 63) == 0) red_lds[i >> 6] = g;
  __syncthreads();

  if (i == 0) out[b] = forward - (red_lds[0] + red_lds[1]);
}

extern "C" void kernel_launch(void* const* d_in, const int* in_sizes, int n_in,
                              void* d_out, int out_size, void* d_ws, size_t ws_size,
                              hipStream_t stream) {
  const float* feats = (const float*)d_in[0];
  const float* trans = (const float*)d_in[1];
  const int* tags = (const int*)d_in[2];
  float* out = (float*)d_out;
  int B = in_sizes[0] / (T_LEN * N_TAG);  // 512
  crf_nll_kernel<<<B, N_TAG, 0, stream>>>(feats, trans, tags, out, T_LEN);
}

// Round 6
// 578.335 us; speedup vs baseline: 1.6117x; 1.6117x over previous
//
#include <hip/hip_runtime.h>

#define N_TAG 128
#define T_LEN 512
#define START_TAG 126
#define STOP_TAG 127

// One block per batch, 256 threads. Thread (i = tid>>1, h = tid&1) owns output
// tag i and j-half h. Exp-space DP: u[j] = exp(alpha[j] - logZ), renormalized
// by max every 4 steps. Per step:
//   part_ih = sum_{j in half h} u[j] * E[i][j]   (E = exp(trans), 64 regs/thread)
//   v_i = part_i0 + part_i1                      (__shfl_xor lane-pair combine)
//   u'_i = v_i * exp(feat_t[i])
// E slice is 64 floats/thread -> provably fits VGPR budget (round-3 failure was
// a partial spill of E[128] at VGPR_Count=96, WRITE_SIZE=18.9MB of scratch).
__global__ __launch_bounds__(256, 2) void crf_nll_kernel(
    const float* __restrict__ feats, const float* __restrict__ trans,
    const int* __restrict__ tags, float* __restrict__ out, int T) {
  const int b = blockIdx.x;
  const int tid = threadIdx.x;
  const int i = tid >> 1;   // output tag
  const int h = tid & 1;    // j-half
  const int lane = tid & 63;
  const int wv = tid >> 6;

  __shared__ float u_lds[2][N_TAG];
  __shared__ float red_lds[4];

  // ---- prologue: E[i][64h .. 64h+63] = exp(trans[i][...]) into 64 VGPRs ----
  float E[64];
  {
    const float4* trow =
        reinterpret_cast<const float4*>(trans + (size_t)i * N_TAG + h * 64);
#pragma unroll
    for (int c = 0; c < 16; ++c) {
      float4 v = trow[c];
      E[4 * c + 0] = __expf(v.x);
      E[4 * c + 1] = __expf(v.y);
      E[4 * c + 2] = __expf(v.z);
      E[4 * c + 3] = __expf(v.w);
    }
  }

  // init: alpha_0 = NEG_INF except START=0  ->  u = one-hot(START)
  if (h == 0) u_lds[0][i] = (i == START_TAG) ? 1.0f : 0.0f;
  float logZ = 0.0f;
  __syncthreads();

  const float* fb = feats + (size_t)b * T * N_TAG;
  // 2-deep feat prefetch pipeline
  float f0 = fb[i];
  float f1 = (T > 1) ? fb[N_TAG + i] : 0.0f;
  int cur = 0;
  float up = 0.0f;

  for (int t = 0; t < T; ++t) {
    float f2 = 0.0f;
    if (t + 2 < T) f2 = fb[(size_t)(t + 2) * N_TAG + i];
    float ef = __expf(f0);

    // half-dot: 16 b128 broadcasts + 64 FMA
    const float4* u4 = reinterpret_cast<const float4*>(u_lds[cur]) + 16 * h;
    float v0 = 0.0f, v1 = 0.0f, v2 = 0.0f, v3 = 0.0f;
#pragma unroll
    for (int c = 0; c < 16; ++c) {
      float4 u = u4[c];
      v0 = __builtin_fmaf(u.x, E[4 * c + 0], v0);
      v1 = __builtin_fmaf(u.y, E[4 * c + 1], v1);
      v2 = __builtin_fmaf(u.z, E[4 * c + 2], v2);
      v3 = __builtin_fmaf(u.w, E[4 * c + 3], v3);
    }
    float part = (v0 + v1) + (v2 + v3);
    part += __shfl_xor(part, 1);  // combine j-halves (lane pair)
    up = part * ef;

    if ((t & 3) == 3) {
      // renormalize: c = max_i u'_i ; u' /= c ; logZ += log(c)
      float m = up;
#pragma unroll
      for (int s = 32; s; s >>= 1) m = fmaxf(m, __shfl_xor(m, s));
      if (lane == 0) red_lds[wv] = m;
      __syncthreads();
      float c4 = fmaxf(fmaxf(red_lds[0], red_lds[1]),
                       fmaxf(red_lds[2], red_lds[3]));
      up *= (1.0f / c4);
      logZ += __logf(c4);
    }

    if (h == 0) u_lds[cur ^ 1][i] = up;
    __syncthreads();
    cur ^= 1;
    f0 = f1;
    f1 = f2;
  }

  // ---- forward score: log(sum_i u_i * exp(trans[STOP][i])) + logZ ----
  float w = (h == 0) ? up * __expf(trans[STOP_TAG * N_TAG + i]) : 0.0f;
#pragma unroll
  for (int s = 32; s; s >>= 1) w += __shfl_xor(w, s);
  __syncthreads();  // guard red_lds reuse
  if (lane == 0) red_lds[wv] = w;
  __syncthreads();
  float forward =
      __logf(red_lds[0] + red_lds[1] + red_lds[2] + red_lds[3]) + logZ;

  // ---- gold path score ----
  const int* tg = tags + (size_t)b * T;
  float g = 0.0f;
  for (int t = tid; t < T; t += 256) {
    int tag = tg[t];
    int prev = (t == 0) ? START_TAG : tg[t - 1];
    g += trans[(size_t)tag * N_TAG + prev] + fb[(size_t)t * N_TAG + tag];
  }
  if (tid == 0) g += trans[STOP_TAG * N_TAG + tg[T - 1]];
#pragma unroll
  for (int s = 32; s; s >>= 1) g += __shfl_xor(g, s);
  __syncthreads();  // guard red_lds reuse (forward already in registers)
  if (lane == 0) red_lds[wv] = g;
  __syncthreads();

  if (tid == 0)
    out[b] = forward - (red_lds[0] + red_lds[1] + red_lds[2] + red_lds[3]);
}

extern "C" void kernel_launch(void* const* d_in, const int* in_sizes, int n_in,
                              void* d_out, int out_size, void* d_ws, size_t ws_size,
                              hipStream_t stream) {
  const float* feats = (const float*)d_in[0];
  const float* trans = (const float*)d_in[1];
  const int* tags = (const int*)d_in[2];
  float* out = (float*)d_out;
  int B = in_sizes[0] / (T_LEN * N_TAG);  // 512
  crf_nll_kernel<<<B, 256, 0, stream>>>(feats, trans, tags, out, T_LEN);
}

// Round 7
// 217.376 us; speedup vs baseline: 4.2879x; 2.6605x over previous
//
#include <hip/hip_runtime.h>
#include <hip/hip_bf16.h>

#define N_TAG 128
#define T_LEN 512
#define START_TAG 126
#define STOP_TAG 127
#define PADJ 136  // bf16 elems per u-row: 272B stride, 16B-aligned

typedef __attribute__((ext_vector_type(8))) __bf16 bf16x8;
typedef __attribute__((ext_vector_type(4))) __bf16 bf16x4;
typedef __attribute__((ext_vector_type(4))) float f32x4;

// Exp-space CRF forward DP via MFMA. 2 batches/block, 256 blocks (1/CU).
// State u[j][n] (tag j, batch-col n) in bf16 LDS, double-buffered.
// Per step: V(128x16) = E(128x128)·U(128x16) via 8x mfma_f32_16x16x32_bf16
// per wave-pair-of-M-tiles; u'[i][n] = V[i][n]*exp(feat_t[n][i]); renorm by
// column max every 4 steps (fp32 range: growth ~5e6/step, 4 steps << 3.4e38).
// E = exp(trans) lives in bf16 A-fragments (32 VGPRs/lane) - no big arrays.
// Only cols n<2 are real batches; cols 2..15 shadow them (n&1) harmlessly.
__global__ __attribute__((amdgpu_flat_work_group_size(256, 256),
                          amdgpu_waves_per_eu(1, 1)))
void crf_mfma_kernel(const float* __restrict__ feats,
                     const float* __restrict__ trans,
                     const int* __restrict__ tags,
                     float* __restrict__ out, int T) {
  const int tid = threadIdx.x;
  const int w = tid >> 6;    // wave: owns tag rows [32w, 32w+32)
  const int lane = tid & 63;
  const int n = lane & 15;   // batch column
  const int g = lane >> 4;   // lane group (k-slot / row-group)
  const int bbase = blockIdx.x * 2;
  const int nn = n & 1;

  __shared__ __align__(16) __bf16 u_lds[2][16 * PADJ];
  __shared__ __align__(16) float red_lds[16][4];
  __shared__ float gold_lds[4];

  // ---- init u0 = one-hot(START) for all 16 columns ----
  for (int idx = tid; idx < 16 * PADJ; idx += 256)
    u_lds[0][idx] = (__bf16)(((idx % PADJ) == START_TAG) ? 1.0f : 0.0f);

  // ---- A-frags: a{m}[kk] lane holds E[32w+16m+n][32kk+8g+j], j=0..7 ----
  bf16x8 a0[4], a1[4];
#pragma unroll
  for (int kk = 0; kk < 4; ++kk) {
    {
      const float* p = trans + (size_t)(32 * w + n) * N_TAG + 32 * kk + 8 * g;
      f32x4 x = *(const f32x4*)(p);
      f32x4 y = *(const f32x4*)(p + 4);
      bf16x8 v;
      v[0] = (__bf16)__expf(x[0]); v[1] = (__bf16)__expf(x[1]);
      v[2] = (__bf16)__expf(x[2]); v[3] = (__bf16)__expf(x[3]);
      v[4] = (__bf16)__expf(y[0]); v[5] = (__bf16)__expf(y[1]);
      v[6] = (__bf16)__expf(y[2]); v[7] = (__bf16)__expf(y[3]);
      a0[kk] = v;
    }
    {
      const float* p = trans + (size_t)(32 * w + 16 + n) * N_TAG + 32 * kk + 8 * g;
      f32x4 x = *(const f32x4*)(p);
      f32x4 y = *(const f32x4*)(p + 4);
      bf16x8 v;
      v[0] = (__bf16)__expf(x[0]); v[1] = (__bf16)__expf(x[1]);
      v[2] = (__bf16)__expf(x[2]); v[3] = (__bf16)__expf(x[3]);
      v[4] = (__bf16)__expf(y[0]); v[5] = (__bf16)__expf(y[1]);
      v[6] = (__bf16)__expf(y[2]); v[7] = (__bf16)__expf(y[3]);
      a1[kk] = v;
    }
  }
  __syncthreads();

  const float* fbase =
      feats + (size_t)(bbase + nn) * T * N_TAG + 32 * w + 4 * g;

  f32x4 up0, up1;
  float logZ = 0.0f;

#define LOADG(D0_, D1_, T_)                           \
  do {                                                \
    const float* p_ = fbase + (size_t)(T_) * N_TAG;   \
    D0_ = *(const f32x4*)(p_);                        \
    D1_ = *(const f32x4*)(p_ + 16);                   \
  } while (0)

#define STEP(PAR_, F0_, F1_, DOREN_)                                         \
  do {                                                                       \
    const __bf16* ub_ = u_lds[PAR_];                                         \
    bf16x8 b0_ = *(const bf16x8*)(ub_ + n * PADJ + 8 * g);                   \
    bf16x8 b1_ = *(const bf16x8*)(ub_ + n * PADJ + 32 + 8 * g);              \
    bf16x8 b2_ = *(const bf16x8*)(ub_ + n * PADJ + 64 + 8 * g);              \
    bf16x8 b3_ = *(const bf16x8*)(ub_ + n * PADJ + 96 + 8 * g);              \
    f32x4 acc0_ = {0.f, 0.f, 0.f, 0.f};                                      \
    f32x4 acc1_ = {0.f, 0.f, 0.f, 0.f};                                      \
    acc0_ = __builtin_amdgcn_mfma_f32_16x16x32_bf16(a0[0], b0_, acc0_, 0, 0, 0); \
    acc1_ = __builtin_amdgcn_mfma_f32_16x16x32_bf16(a1[0], b0_, acc1_, 0, 0, 0); \
    acc0_ = __builtin_amdgcn_mfma_f32_16x16x32_bf16(a0[1], b1_, acc0_, 0, 0, 0); \
    acc1_ = __builtin_amdgcn_mfma_f32_16x16x32_bf16(a1[1], b1_, acc1_, 0, 0, 0); \
    acc0_ = __builtin_amdgcn_mfma_f32_16x16x32_bf16(a0[2], b2_, acc0_, 0, 0, 0); \
    acc1_ = __builtin_amdgcn_mfma_f32_16x16x32_bf16(a1[2], b2_, acc1_, 0, 0, 0); \
    acc0_ = __builtin_amdgcn_mfma_f32_16x16x32_bf16(a0[3], b3_, acc0_, 0, 0, 0); \
    acc1_ = __builtin_amdgcn_mfma_f32_16x16x32_bf16(a1[3], b3_, acc1_, 0, 0, 0); \
    up0[0] = acc0_[0] * __expf(F0_[0]); up0[1] = acc0_[1] * __expf(F0_[1]);  \
    up0[2] = acc0_[2] * __expf(F0_[2]); up0[3] = acc0_[3] * __expf(F0_[3]);  \
    up1[0] = acc1_[0] * __expf(F1_[0]); up1[1] = acc1_[1] * __expf(F1_[1]);  \
    up1[2] = acc1_[2] * __expf(F1_[2]); up1[3] = acc1_[3] * __expf(F1_[3]);  \
    if (DOREN_) {                                                            \
      float mx_ = fmaxf(fmaxf(fmaxf(up0[0], up0[1]), fmaxf(up0[2], up0[3])), \
                        fmaxf(fmaxf(up1[0], up1[1]), fmaxf(up1[2], up1[3]))); \
      mx_ = fmaxf(mx_, __shfl_xor(mx_, 16));                                 \
      mx_ = fmaxf(mx_, __shfl_xor(mx_, 32));                                 \
      if (g == 0) red_lds[n][w] = mx_;                                       \
      __syncthreads();                                                       \
      f32x4 rm_ = *(const f32x4*)red_lds[n];                                 \
      float c_ = fmaxf(fmaxf(rm_[0], rm_[1]), fmaxf(rm_[2], rm_[3]));        \
      float inv_ = 1.0f / c_;                                                \
      up0[0] *= inv_; up0[1] *= inv_; up0[2] *= inv_; up0[3] *= inv_;        \
      up1[0] *= inv_; up1[1] *= inv_; up1[2] *= inv_; up1[3] *= inv_;        \
      logZ += __logf(c_);                                                    \
    }                                                                        \
    __bf16* ud_ = u_lds[(PAR_) ^ 1];                                         \
    bf16x4 w0_, w1_;                                                         \
    w0_[0] = (__bf16)up0[0]; w0_[1] = (__bf16)up0[1];                        \
    w0_[2] = (__bf16)up0[2]; w0_[3] = (__bf16)up0[3];                        \
    w1_[0] = (__bf16)up1[0]; w1_[1] = (__bf16)up1[1];                        \
    w1_[2] = (__bf16)up1[2]; w1_[3] = (__bf16)up1[3];                        \
    *(bf16x4*)(ud_ + n * PADJ + 32 * w + 4 * g) = w0_;                       \
    *(bf16x4*)(ud_ + n * PADJ + 32 * w + 16 + 4 * g) = w1_;                  \
    __syncthreads();                                                         \
  } while (0)

  // prologue: prefetch steps 0..7
  f32x4 P00, P01, P10, P11, P20, P21, P30, P31;
  f32x4 Q00, Q01, Q10, Q11, Q20, Q21, Q30, Q31;
  LOADG(P00, P01, 0); LOADG(P10, P11, 1); LOADG(P20, P21, 2); LOADG(P30, P31, 3);
  LOADG(Q00, Q01, 4); LOADG(Q10, Q11, 5); LOADG(Q20, Q21, 6); LOADG(Q30, Q31, 7);

  for (int t0 = 0; t0 < T; t0 += 8) {
    STEP(0, P00, P01, false);
    STEP(1, P10, P11, false);
    STEP(0, P20, P21, false);
    STEP(1, P30, P31, true);
    if (t0 + 8 < T) {
      LOADG(P00, P01, t0 + 8);  LOADG(P10, P11, t0 + 9);
      LOADG(P20, P21, t0 + 10); LOADG(P30, P31, t0 + 11);
    }
    STEP(0, Q00, Q01, false);
    STEP(1, Q10, Q11, false);
    STEP(0, Q20, Q21, false);
    STEP(1, Q30, Q31, true);
    if (t0 + 12 < T) {
      LOADG(Q00, Q01, t0 + 12); LOADG(Q10, Q11, t0 + 13);
      LOADG(Q20, Q21, t0 + 14); LOADG(Q30, Q31, t0 + 15);
    }
  }

  // ---- forward score: log(sum_i u_i * exp(trans[STOP][i])) + logZ ----
  float term = 0.f;
#pragma unroll
  for (int r = 0; r < 4; ++r) {
    term += up0[r] * __expf(trans[STOP_TAG * N_TAG + 32 * w + 4 * g + r]);
    term += up1[r] * __expf(trans[STOP_TAG * N_TAG + 32 * w + 16 + 4 * g + r]);
  }
  term += __shfl_xor(term, 16);
  term += __shfl_xor(term, 32);
  if (g == 0) red_lds[n][w] = term;
  __syncthreads();

  // ---- gold path score (fp32 exact) ----
  const int nb = tid >> 7;  // waves 0,1 -> batch 0; waves 2,3 -> batch 1
  const int tt = tid & 127;
  const int* tg = tags + (size_t)(bbase + nb) * T;
  const float* fg = feats + (size_t)(bbase + nb) * T * N_TAG;
  float gsum = 0.f;
  for (int t = tt; t < T; t += 128) {
    int tag = tg[t];
    int prev = (t == 0) ? START_TAG : tg[t - 1];
    gsum += trans[(size_t)tag * N_TAG + prev] + fg[(size_t)t * N_TAG + tag];
    if (t == T - 1) gsum += trans[STOP_TAG * N_TAG + tag];
  }
#pragma unroll
  for (int s = 32; s; s >>= 1) gsum += __shfl_xor(gsum, s);
  if (lane == 0) gold_lds[w] = gsum;
  __syncthreads();

  if (tid < 2) {
    f32x4 rm = *(const f32x4*)red_lds[tid];
    float S = rm[0] + rm[1] + rm[2] + rm[3];
    float fwd = __logf(S) + logZ;  // lane tid: n == tid, logZ tracks col n
    float gold = gold_lds[2 * tid] + gold_lds[2 * tid + 1];
    out[bbase + tid] = fwd - gold;
  }
#undef STEP
#undef LOADG
}

extern "C" void kernel_launch(void* const* d_in, const int* in_sizes, int n_in,
                              void* d_out, int out_size, void* d_ws, size_t ws_size,
                              hipStream_t stream) {
  const float* feats = (const float*)d_in[0];
  const float* trans = (const float*)d_in[1];
  const int* tags = (const int*)d_in[2];
  float* out = (float*)d_out;
  int B = in_sizes[0] / (T_LEN * N_TAG);  // 512
  crf_mfma_kernel<<<B / 2, 256, 0, stream>>>(feats, trans, tags, out, T_LEN);
}